// Round 1
// baseline (362.790 us; speedup 1.0000x reference)
//
#include <hip/hip_runtime.h>

// GCN pipeline, algebraically collapsed:
//   h1 = relu( (scatter8(norm * x) + self) @ W1 + b1 )        [N,64]
//   g  = (1/N) * (sum_s c[s]*h1[s]) @ W2 + b2                 [1,64]
//   c[s] = dinv[s]*sdeg[s] + dinv[s]^2,  sdeg[s] = sum_{d: s->d} dinv[d]
//   out = concat(g, relu(state@Wm+bm)) @ Wc + bc              [1,2]

__global__ void k_hist(const int* __restrict__ dst, unsigned* __restrict__ degi, int E) {
    int i = blockIdx.x * blockDim.x + threadIdx.x;
    if (i < E) atomicAdd(&degi[dst[i]], 1u);
}

__global__ void k_dinv(const unsigned* __restrict__ degi, float* __restrict__ dinv, int N) {
    int i = blockIdx.x * blockDim.x + threadIdx.x;
    if (i < N) dinv[i] = rsqrtf((float)(degi[i] + 1u));   // +1 self-loop
}

// 8 threads per edge: lane j handles feature j. acc8[d][j] += dinv[s]*dinv[d]*x[s][j]
// lane 0 additionally does sdeg[s] += dinv[d] (layer-2 collapse coefficient).
__global__ void k_scatter(const int* __restrict__ src, const int* __restrict__ dst,
                          const float* __restrict__ x, const float* __restrict__ dinv,
                          float* __restrict__ acc8, float* __restrict__ sdeg, int E) {
    long long t = (long long)blockIdx.x * blockDim.x + threadIdx.x;
    int e = (int)(t >> 3);
    int j = (int)(t & 7);
    if (e >= E) return;
    int s = src[e], d = dst[e];
    float wd = dinv[d];
    float w  = dinv[s] * wd;
    unsafeAtomicAdd(&acc8[(size_t)d * 8 + j], w * x[(size_t)s * 8 + j]);
    if (j == 0) unsafeAtomicAdd(&sdeg[s], wd);
}

// One wave-lane per output column k (k = lane). Each wave owns a strided set of
// nodes; computes h1[n][k] = relu(sum_j a8[j]*W1[j][k] + b1[k]) and accumulates
// vacc += c[n]*h1. Block-reduces 4 waves -> vpart[block][64].
__launch_bounds__(256)
__global__ void k_node(const float* __restrict__ x, const float* __restrict__ dinv,
                       const float* __restrict__ acc8, const float* __restrict__ sdeg,
                       const float* __restrict__ W1, const float* __restrict__ b1,
                       float* __restrict__ vpart, int N, int nwaves_total) {
    int lane = threadIdx.x & 63;
    int wid  = (blockIdx.x * blockDim.x + threadIdx.x) >> 6;

    float w1[8];
#pragma unroll
    for (int j = 0; j < 8; ++j) w1[j] = W1[j * 64 + lane];
    float bb = b1[lane];

    float vacc = 0.f;
    for (int n = wid; n < N; n += nwaves_total) {
        float di   = dinv[n];
        float self = di * di;
        float c    = fmaf(di, sdeg[n], self);
        float h    = bb;
#pragma unroll
        for (int j = 0; j < 8; ++j) {
            float a = fmaf(self, x[(size_t)n * 8 + j], acc8[(size_t)n * 8 + j]);
            h = fmaf(a, w1[j], h);
        }
        h = fmaxf(h, 0.f);
        vacc = fmaf(c, h, vacc);
    }

    __shared__ float red[256];
    red[threadIdx.x] = vacc;
    __syncthreads();
    if (threadIdx.x < 64) {
        float v = red[threadIdx.x] + red[threadIdx.x + 64] +
                  red[threadIdx.x + 128] + red[threadIdx.x + 192];
        vpart[blockIdx.x * 64 + threadIdx.x] = v;
    }
}

// Single block, 64 threads: reduce vpart, g = (1/N)*v@W2 + b2,
// s = relu(state@Wm+bm), out = [g,s]@Wc + bc.
__global__ void k_final(const float* __restrict__ vpart, int NB,
                        const float* __restrict__ W2, const float* __restrict__ b2,
                        const float* __restrict__ state, const float* __restrict__ Wm,
                        const float* __restrict__ bm, const float* __restrict__ Wc,
                        const float* __restrict__ bc, float* __restrict__ out,
                        float inv_n) {
    __shared__ float v[64];
    __shared__ float gs[128];
    int k = threadIdx.x;   // blockDim = 64

    float acc = 0.f;
    for (int b = 0; b < NB; ++b) acc += vpart[b * 64 + k];
    v[k] = acc;
    __syncthreads();

    float g = 0.f;
    for (int j = 0; j < 64; ++j) g = fmaf(v[j], W2[j * 64 + k], g);
    g = fmaf(g, inv_n, b2[k]);

    float s = bm[k];
    for (int j = 0; j < 8; ++j) s = fmaf(state[j], Wm[j * 64 + k], s);
    s = fmaxf(s, 0.f);

    gs[k] = g;
    gs[64 + k] = s;
    __syncthreads();

    if (k < 2) {
        float o = bc[k];
        for (int j = 0; j < 128; ++j) o = fmaf(gs[j], Wc[j * 2 + k], o);
        out[k] = o;
    }
}

extern "C" void kernel_launch(void* const* d_in, const int* in_sizes, int n_in,
                              void* d_out, int out_size, void* d_ws, size_t ws_size,
                              hipStream_t stream) {
    const float* x     = (const float*)d_in[0];
    const float* state = (const float*)d_in[1];
    const float* W1    = (const float*)d_in[2];
    const float* b1    = (const float*)d_in[3];
    const float* W2    = (const float*)d_in[4];
    const float* b2    = (const float*)d_in[5];
    const float* Wm    = (const float*)d_in[6];
    const float* bm    = (const float*)d_in[7];
    const float* Wc    = (const float*)d_in[8];
    const float* bc    = (const float*)d_in[9];
    const int*   ei    = (const int*)d_in[10];

    const int N = in_sizes[0] / 8;
    const int E = in_sizes[10] / 2;
    const int* src = ei;
    const int* dst = ei + E;

    // Workspace layout (zeroed region first; dinv needs no init).
    char* ws = (char*)d_ws;
    size_t off = 0;
    auto alloc = [&](size_t bytes) -> void* {
        void* p = ws + off;
        off += (bytes + 255) & ~(size_t)255;
        return p;
    };
    unsigned* degi  = (unsigned*)alloc((size_t)N * 4);
    float*    acc8  = (float*)   alloc((size_t)N * 8 * 4);
    float*    sdeg  = (float*)   alloc((size_t)N * 4);
    const int NB = 120;
    float*    vpart = (float*)   alloc((size_t)NB * 64 * 4);
    size_t zero_bytes = off;                 // everything above needs zeroing
    float*    dinv  = (float*)   alloc((size_t)N * 4);
    (void)ws_size; (void)n_in; (void)out_size;

    hipMemsetAsync(d_ws, 0, zero_bytes, stream);

    int b256;
    b256 = (E + 255) / 256;
    k_hist<<<b256, 256, 0, stream>>>(dst, degi, E);

    b256 = (N + 255) / 256;
    k_dinv<<<b256, 256, 0, stream>>>(degi, dinv, N);

    long long tscatter = (long long)E * 8;
    b256 = (int)((tscatter + 255) / 256);
    k_scatter<<<b256, 256, 0, stream>>>(src, dst, x, dinv, acc8, sdeg, E);

    k_node<<<NB, 256, 0, stream>>>(x, dinv, acc8, sdeg, W1, b1, vpart, N, NB * 4);

    k_final<<<1, 64, 0, stream>>>(vpart, NB, W2, b2, state, Wm, bm, Wc, bc,
                                  (float*)d_out, 1.0f / (float)N);
}